// Round 1
// baseline (1407.852 us; speedup 1.0000x reference)
//
#include <hip/hip_runtime.h>
#include <math.h>

// ---------------------------------------------------------------------------
// GAT 3-layer net, fp32 baseline.
// Pipeline per call:
//   CSR build (deg count -> scan -> scatter)  [edge_index fixed, but ws is
//   re-poisoned each call so we rebuild every launch]
//   L1: H=nf@W1, B=nf@Wl1+bl1, attn dots, aggregate(in-place into B, ELU)
//   L2: H=B@W2,  C=B@Wl2+bl2, attn dots, aggregate(in-place into C, ELU)
//   L3: h3=C@W3, lin3=C@Wl3+bl3, attn3, fused mean-head + log_softmax -> out
// ---------------------------------------------------------------------------

__device__ __forceinline__ float leaky(float x){ return x > 0.f ? x : 0.2f * x; }

// ---------------- CSR build ----------------
__global__ void k_count(const int* __restrict__ ei, int* __restrict__ deg, int E){
  int e = blockIdx.x * blockDim.x + threadIdx.x;
  if (e < E) atomicAdd(&deg[ei[E + e]], 1);
}

__global__ void k_scan(const int* __restrict__ deg, int* __restrict__ rp, int n){
  // single block, 1024 threads, exclusive scan of deg[0..n) -> rp[0..n]
  __shared__ int part[1024];
  int t = threadIdx.x;
  int K = (n + 1023) >> 10;     // elems per thread (<=16 for n<=16384)
  int vals[16];
  int start = t * K;
  int local = 0;
  for (int j = 0; j < K; j++){
    int idx = start + j;
    int v = (idx < n) ? deg[idx] : 0;
    vals[j] = local;            // exclusive within chunk
    local += v;
  }
  part[t] = local;
  __syncthreads();
  for (int off = 1; off < 1024; off <<= 1){
    int v = (t >= off) ? part[t - off] : 0;
    __syncthreads();
    part[t] += v;               // inclusive scan of chunk sums
    __syncthreads();
  }
  int base = part[t] - local;   // exclusive base for this chunk
  for (int j = 0; j < K; j++){
    int idx = start + j;
    if (idx < n) rp[idx] = base + vals[j];
  }
  if (t == 1023) rp[n] = part[1023];
}

__global__ void k_cursor(const int* __restrict__ rp, int* __restrict__ cur, int n){
  int i = blockIdx.x * blockDim.x + threadIdx.x;
  if (i < n) cur[i] = rp[i];
}

__global__ void k_scatter(const int* __restrict__ ei, int* __restrict__ cur,
                          int* __restrict__ col, int E){
  int e = blockIdx.x * blockDim.x + threadIdx.x;
  if (e < E){
    int s = ei[e], d = ei[E + e];
    int p = atomicAdd(&cur[d], 1);
    col[p] = s;
  }
}

// ---------------- fp32 tiled GEMM: C = A[M,K] @ B[K,N] (+bias) ----------------
#define BM 64
#define BN 64
#define BK 16

__global__ __launch_bounds__(256) void k_gemm(const float* __restrict__ A,
                                              const float* __restrict__ B,
                                              const float* __restrict__ bias,
                                              float* __restrict__ C,
                                              int M, int N, int K){
  __shared__ float As[BK][BM];
  __shared__ float Bs[BK][BN + 4];
  int t  = threadIdx.x;
  int bm = blockIdx.x * BM;
  int bn = blockIdx.y * BN;
  int tx = t & 15, ty = t >> 4;
  float acc[4][4] = {};
  int ar = t >> 2;             // A tile row 0..63
  int ak = (t & 3) << 2;       // A tile k   0,4,8,12
  int br = t >> 4;             // B tile row 0..15
  int bc = (t & 15) << 2;      // B tile col 0..60
  bool nvec = ((N & 3) == 0);  // K is always a multiple of 16 here (512/1024)
  for (int k0 = 0; k0 < K; k0 += BK){
    float4 av = {0, 0, 0, 0};
    int arow = bm + ar;
    if (arow < M) av = *(const float4*)(A + (size_t)arow * K + (k0 + ak));
    As[ak + 0][ar] = av.x; As[ak + 1][ar] = av.y;
    As[ak + 2][ar] = av.z; As[ak + 3][ar] = av.w;
    int brow = k0 + br;
    int bcol = bn + bc;
    float4 bv = {0, 0, 0, 0};
    if (nvec){
      if (bcol < N) bv = *(const float4*)(B + (size_t)brow * N + bcol);
    } else {
      float tmp[4] = {0, 0, 0, 0};
      for (int j = 0; j < 4; j++)
        if (bcol + j < N) tmp[j] = B[(size_t)brow * N + bcol + j];
      bv = make_float4(tmp[0], tmp[1], tmp[2], tmp[3]);
    }
    *(float4*)&Bs[br][bc] = bv;
    __syncthreads();
#pragma unroll
    for (int kk = 0; kk < BK; kk++){
      float a0 = As[kk][ty * 4 + 0], a1 = As[kk][ty * 4 + 1];
      float a2 = As[kk][ty * 4 + 2], a3 = As[kk][ty * 4 + 3];
      float4 b4 = *(float4*)&Bs[kk][tx * 4];
      acc[0][0] += a0 * b4.x; acc[0][1] += a0 * b4.y; acc[0][2] += a0 * b4.z; acc[0][3] += a0 * b4.w;
      acc[1][0] += a1 * b4.x; acc[1][1] += a1 * b4.y; acc[1][2] += a1 * b4.z; acc[1][3] += a1 * b4.w;
      acc[2][0] += a2 * b4.x; acc[2][1] += a2 * b4.y; acc[2][2] += a2 * b4.z; acc[2][3] += a2 * b4.w;
      acc[3][0] += a3 * b4.x; acc[3][1] += a3 * b4.y; acc[3][2] += a3 * b4.z; acc[3][3] += a3 * b4.w;
    }
    __syncthreads();
  }
#pragma unroll
  for (int r = 0; r < 4; r++){
    int row = bm + ty * 4 + r;
    if (row >= M) continue;
#pragma unroll
    for (int c = 0; c < 4; c++){
      int colx = bn + tx * 4 + c;
      if (colx < N){
        float v = acc[r][c];
        if (bias) v += bias[colx];
        C[(size_t)row * N + colx] = v;
      }
    }
  }
}

// ---------------- attention dot products: als/ald [N,4] (layers 1/2) ----------------
__global__ __launch_bounds__(256) void k_attn_dots(const float* __restrict__ h,
                                                   const float* __restrict__ a_s,
                                                   const float* __restrict__ a_d,
                                                   float* __restrict__ als,
                                                   float* __restrict__ ald, int N){
  int i = blockIdx.x;
  int t = threadIdx.x;          // 256 threads; wave w handles head w (64 lanes x 4ch = 256ch)
  const float4* h4 = (const float4*)(h + (size_t)i * 1024);
  float4 hv = h4[t];
  float4 sv = ((const float4*)a_s)[t];
  float4 dv = ((const float4*)a_d)[t];
  float ps = hv.x * sv.x + hv.y * sv.y + hv.z * sv.z + hv.w * sv.w;
  float pd = hv.x * dv.x + hv.y * dv.y + hv.z * dv.z + hv.w * dv.w;
#pragma unroll
  for (int off = 32; off >= 1; off >>= 1){
    ps += __shfl_down(ps, off);
    pd += __shfl_down(pd, off);
  }
  if ((t & 63) == 0){
    int w = t >> 6;
    als[i * 4 + w] = ps;
    ald[i * 4 + w] = pd;
  }
}

// ---------------- GAT aggregation (layers 1/2): Y[i] = elu(Y[i] + b + sum alpha*H[src]) ----------------
__global__ __launch_bounds__(256) void k_agg(const float* __restrict__ H,
                                             float* __restrict__ Y,
                                             const float* __restrict__ bias,
                                             const float* __restrict__ als,
                                             const float* __restrict__ ald,
                                             const int* __restrict__ rp,
                                             const int* __restrict__ col, int doElu){
  int i = blockIdx.x;
  int t = threadIdx.x;
  int lane = t & 63;
  int w = t >> 6;                 // head for phase 1 and channel group for phase 2
  int ro = rp[i];
  int deg = rp[i + 1] - ro;
  __shared__ float sm[4], ss[4];
  __shared__ float s_alpha[64][4];
  __shared__ int s_src[64];

  // phase 1: per-head online softmax (max + sum) over incoming edges + self loop
  float aldw = ald[i * 4 + w];
  float eself = leaky(als[i * 4 + w] + aldw);
  float m = eself;                     // every lane starts at self max (avoids -inf)
  float s = (lane == 0) ? 1.f : 0.f;   // self term exp(eself - eself) counted once
  for (int e = lane; e < deg; e += 64){
    int src = col[ro + e];
    float ev = leaky(als[src * 4 + w] + aldw);
    float M = fmaxf(m, ev);
    s = s * __expf(m - M) + __expf(ev - M);
    m = M;
  }
#pragma unroll
  for (int off = 32; off >= 1; off >>= 1){
    float mo = __shfl_down(m, off);
    float so = __shfl_down(s, off);
    float M = fmaxf(m, mo);
    s = s * __expf(m - M) + so * __expf(mo - M);
    m = M;
  }
  if (lane == 0){ sm[w] = m; ss[w] = s; }
  __syncthreads();

  // phase 2: accumulate; thread t owns channels 4t..4t+3 (head = t>>6)
  int head = t >> 6;
  float mh = sm[head];
  float inv = 1.f / (ss[head] + 1e-16f);
  float4 acc = *(const float4*)(Y + (size_t)i * 1024 + t * 4);
  float4 bb  = *(const float4*)(bias + t * 4);
  acc.x += bb.x; acc.y += bb.y; acc.z += bb.z; acc.w += bb.w;
  float aself = __expf(leaky(als[i * 4 + head] + ald[i * 4 + head]) - mh) * inv;
  {
    float4 hv = *(const float4*)(H + (size_t)i * 1024 + t * 4);
    acc.x += aself * hv.x; acc.y += aself * hv.y;
    acc.z += aself * hv.z; acc.w += aself * hv.w;
  }
  for (int base = 0; base < deg; base += 64){
    __syncthreads();
    if (t < 64 && base + t < deg){
      int src = col[ro + base + t];
      s_src[t] = src;
#pragma unroll
      for (int hh = 0; hh < 4; hh++){
        s_alpha[t][hh] = __expf(leaky(als[src * 4 + hh] + ald[i * 4 + hh]) - sm[hh])
                         / (ss[hh] + 1e-16f);
      }
    }
    __syncthreads();
    int nn = min(64, deg - base);
    for (int e = 0; e < nn; e++){
      float a = s_alpha[e][head];
      float4 hv = *(const float4*)(H + (size_t)s_src[e] * 1024 + t * 4);
      acc.x += a * hv.x; acc.y += a * hv.y; acc.z += a * hv.z; acc.w += a * hv.w;
    }
  }
  if (doElu){
    acc.x = acc.x > 0.f ? acc.x : expm1f(acc.x);
    acc.y = acc.y > 0.f ? acc.y : expm1f(acc.y);
    acc.z = acc.z > 0.f ? acc.z : expm1f(acc.z);
    acc.w = acc.w > 0.f ? acc.w : expm1f(acc.w);
  }
  *(float4*)(Y + (size_t)i * 1024 + t * 4) = acc;
}

// ---------------- layer-3 attention dots: [N,6,6] -> als/ald [N,6] ----------------
__global__ void k_attn3(const float* __restrict__ h3, const float* __restrict__ a_s,
                        const float* __restrict__ a_d, float* __restrict__ als,
                        float* __restrict__ ald, int N){
  int i = blockIdx.x * blockDim.x + threadIdx.x;
  if (i >= N) return;
  const float* hp = h3 + (size_t)i * 36;
#pragma unroll
  for (int hh = 0; hh < 6; hh++){
    float s = 0.f, d = 0.f;
#pragma unroll
    for (int c = 0; c < 6; c++){
      float v = hp[hh * 6 + c];
      s += v * a_s[hh * 6 + c];
      d += v * a_d[hh * 6 + c];
    }
    als[i * 6 + hh] = s;
    ald[i * 6 + hh] = d;
  }
}

// ---------------- layer 3: GAT(mean heads) + b3 + lin3, then log_softmax ----------------
__global__ __launch_bounds__(64) void k_layer3(const float* __restrict__ h3,
                                               const float* __restrict__ lin3,
                                               const float* __restrict__ als,
                                               const float* __restrict__ ald,
                                               const float* __restrict__ b3,
                                               const int* __restrict__ rp,
                                               const int* __restrict__ col,
                                               float* __restrict__ out){
  int i = blockIdx.x;
  int lane = threadIdx.x;       // 64 threads = 1 wave
  int ro = rp[i], deg = rp[i + 1] - ro;
  float aldv[6], m[6], s[6];
#pragma unroll
  for (int h = 0; h < 6; h++){
    aldv[h] = ald[i * 6 + h];
    float e = leaky(als[i * 6 + h] + aldv[h]);
    m[h] = e;
    s[h] = (lane == 0) ? 1.f : 0.f;
  }
  for (int e = lane; e < deg; e += 64){
    int src = col[ro + e];
#pragma unroll
    for (int h = 0; h < 6; h++){
      float ev = leaky(als[src * 6 + h] + aldv[h]);
      float M = fmaxf(m[h], ev);
      s[h] = s[h] * __expf(m[h] - M) + __expf(ev - M);
      m[h] = M;
    }
  }
#pragma unroll
  for (int off = 32; off >= 1; off >>= 1){
#pragma unroll
    for (int h = 0; h < 6; h++){
      float mo = __shfl_down(m[h], off);
      float so = __shfl_down(s[h], off);
      float M = fmaxf(m[h], mo);
      s[h] = s[h] * __expf(m[h] - M) + so * __expf(mo - M);
      m[h] = M;
    }
  }
#pragma unroll
  for (int h = 0; h < 6; h++){ m[h] = __shfl(m[h], 0); s[h] = __shfl(s[h], 0); }

  __shared__ float o36[36];
  __shared__ float o6[6];
  if (lane < 36){
    int hh = lane / 6, cc = lane - hh * 6;
    float inv = 1.f / (s[hh] + 1e-16f);
    float acc = __expf(leaky(als[i * 6 + hh] + aldv[hh]) - m[hh]) * inv
                * h3[(size_t)i * 36 + hh * 6 + cc];
    for (int e = 0; e < deg; e++){
      int src = col[ro + e];
      float a = __expf(leaky(als[src * 6 + hh] + aldv[hh]) - m[hh]) * inv;
      acc += a * h3[(size_t)src * 36 + hh * 6 + cc];
    }
    o36[lane] = acc;
  }
  __syncthreads();
  if (lane < 6){
    float v = 0.f;
#pragma unroll
    for (int h = 0; h < 6; h++) v += o36[h * 6 + lane];
    o6[lane] = v * (1.f / 6.f) + b3[lane] + lin3[i * 6 + lane];
  }
  __syncthreads();
  if (lane == 0){
    float mx = o6[0];
    for (int c = 1; c < 6; c++) mx = fmaxf(mx, o6[c]);
    float se = 0.f;
    for (int c = 0; c < 6; c++) se += __expf(o6[c] - mx);
    float lse = logf(se);
    for (int c = 0; c < 6; c++) out[(size_t)i * 6 + c] = o6[c] - mx - lse;
  }
}

// ---------------------------------------------------------------------------
extern "C" void kernel_launch(void* const* d_in, const int* in_sizes, int n_in,
                              void* d_out, int out_size, void* d_ws, size_t ws_size,
                              hipStream_t stream){
  const float* nf  = (const float*)d_in[0];
  const int*   ei  = (const int*)d_in[1];
  const float* W1  = (const float*)d_in[2];
  const float* as1 = (const float*)d_in[3];
  const float* ad1 = (const float*)d_in[4];
  const float* b1  = (const float*)d_in[5];
  const float* Wl1 = (const float*)d_in[6];
  const float* bl1 = (const float*)d_in[7];
  const float* W2  = (const float*)d_in[8];
  const float* as2 = (const float*)d_in[9];
  const float* ad2 = (const float*)d_in[10];
  const float* b2  = (const float*)d_in[11];
  const float* Wl2 = (const float*)d_in[12];
  const float* bl2 = (const float*)d_in[13];
  const float* W3  = (const float*)d_in[14];
  const float* as3 = (const float*)d_in[15];
  const float* ad3 = (const float*)d_in[16];
  const float* b3  = (const float*)d_in[17];
  const float* Wl3 = (const float*)d_in[18];
  const float* bl3 = (const float*)d_in[19];
  float* out = (float*)d_out;

  const int N = in_sizes[0] / 512;   // 10000
  const int E = in_sizes[1] / 2;     // 160000

  char* ws = (char*)d_ws;
  size_t off = 0;
  auto alloc = [&](size_t bytes) -> char* {
    char* p = ws + off;
    off += (bytes + 255) & ~(size_t)255;
    return p;
  };
  float* Hb   = (float*)alloc((size_t)N * 1024 * 4);
  float* Bb   = (float*)alloc((size_t)N * 1024 * 4);
  float* Cb   = (float*)alloc((size_t)N * 1024 * 4);
  float* h3   = (float*)alloc((size_t)N * 36 * 4);
  float* lin3 = (float*)alloc((size_t)N * 6 * 4);
  float* als  = (float*)alloc((size_t)N * 8 * 4);
  float* ald  = (float*)alloc((size_t)N * 8 * 4);
  int* deg    = (int*)alloc((size_t)N * 4);
  int* rp     = (int*)alloc((size_t)(N + 1) * 4);
  int* cur    = (int*)alloc((size_t)N * 4);
  int* colx   = (int*)alloc((size_t)E * 4);

  // CSR build (ws is re-poisoned every call, so rebuild every call)
  hipMemsetAsync(deg, 0, (size_t)N * 4, stream);
  k_count  <<<(E + 255) / 256, 256, 0, stream>>>(ei, deg, E);
  k_scan   <<<1, 1024, 0, stream>>>(deg, rp, N);
  k_cursor <<<(N + 255) / 256, 256, 0, stream>>>(rp, cur, N);
  k_scatter<<<(E + 255) / 256, 256, 0, stream>>>(ei, cur, colx, E);

  dim3 blk(256);
  dim3 g1((N + 63) / 64, 1024 / 64);
  // layer 1
  k_gemm<<<g1, blk, 0, stream>>>(nf, W1, nullptr, Hb, N, 1024, 512);
  k_gemm<<<g1, blk, 0, stream>>>(nf, Wl1, bl1, Bb, N, 1024, 512);
  k_attn_dots<<<N, 256, 0, stream>>>(Hb, as1, ad1, als, ald, N);
  k_agg<<<N, 256, 0, stream>>>(Hb, Bb, b1, als, ald, rp, colx, 1);
  // layer 2
  k_gemm<<<g1, blk, 0, stream>>>(Bb, W2, nullptr, Hb, N, 1024, 1024);
  k_gemm<<<g1, blk, 0, stream>>>(Bb, Wl2, bl2, Cb, N, 1024, 1024);
  k_attn_dots<<<N, 256, 0, stream>>>(Hb, as2, ad2, als, ald, N);
  k_agg<<<N, 256, 0, stream>>>(Hb, Cb, b2, als, ald, rp, colx, 1);
  // layer 3
  dim3 g3((N + 63) / 64, 1);
  k_gemm<<<g3, blk, 0, stream>>>(Cb, W3, nullptr, h3, N, 36, 1024);
  k_gemm<<<g3, blk, 0, stream>>>(Cb, Wl3, bl3, lin3, N, 6, 1024);
  k_attn3<<<(N + 255) / 256, 256, 0, stream>>>(h3, as3, ad3, als, ald, N);
  k_layer3<<<N, 64, 0, stream>>>(h3, lin3, als, ald, b3, rp, colx, out);
}

// Round 2
// 616.887 us; speedup vs baseline: 2.2822x; 2.2822x over previous
//
#include <hip/hip_runtime.h>
#include <math.h>

// ---------------------------------------------------------------------------
// GAT 3-layer net. R2: big GEMMs in bf16 MFMA (16x16x32, 128x128 tile,
// global_load_lds width=16, B pre-transposed to [N,K] bf16). H kept in bf16
// to halve k_agg gather traffic. Linear-path activations stay fp32.
// ---------------------------------------------------------------------------

__device__ __forceinline__ float leaky(float x){ return x > 0.f ? x : 0.2f * x; }

__device__ __forceinline__ float bf2f(unsigned short u){
  union { unsigned int i; float f; } v; v.i = ((unsigned int)u) << 16; return v.f;
}
__device__ __forceinline__ unsigned short f2bf(float f){
  union { float f; unsigned int i; } v; v.f = f;
  unsigned int r = v.i + 0x7FFF + ((v.i >> 16) & 1);   // RNE
  return (unsigned short)(r >> 16);
}
__device__ __forceinline__ float4 loadbf4(const unsigned short* p){
  ushort4 u = *(const ushort4*)p;
  return make_float4(bf2f(u.x), bf2f(u.y), bf2f(u.z), bf2f(u.w));
}

// ---------------- CSR build ----------------
__global__ void k_count(const int* __restrict__ ei, int* __restrict__ deg, int E){
  int e = blockIdx.x * blockDim.x + threadIdx.x;
  if (e < E) atomicAdd(&deg[ei[E + e]], 1);
}

__global__ void k_scan(const int* __restrict__ deg, int* __restrict__ rp, int n){
  __shared__ int part[1024];
  int t = threadIdx.x;
  int K = (n + 1023) >> 10;
  int vals[16];
  int start = t * K;
  int local = 0;
  for (int j = 0; j < K; j++){
    int idx = start + j;
    int v = (idx < n) ? deg[idx] : 0;
    vals[j] = local;
    local += v;
  }
  part[t] = local;
  __syncthreads();
  for (int off = 1; off < 1024; off <<= 1){
    int v = (t >= off) ? part[t - off] : 0;
    __syncthreads();
    part[t] += v;
    __syncthreads();
  }
  int base = part[t] - local;
  for (int j = 0; j < K; j++){
    int idx = start + j;
    if (idx < n) rp[idx] = base + vals[j];
  }
  if (t == 1023) rp[n] = part[1023];
}

__global__ void k_cursor(const int* __restrict__ rp, int* __restrict__ cur, int n){
  int i = blockIdx.x * blockDim.x + threadIdx.x;
  if (i < n) cur[i] = rp[i];
}

__global__ void k_scatter(const int* __restrict__ ei, int* __restrict__ cur,
                          int* __restrict__ col, int E){
  int e = blockIdx.x * blockDim.x + threadIdx.x;
  if (e < E){
    int s = ei[e], d = ei[E + e];
    int p = atomicAdd(&cur[d], 1);
    col[p] = s;
  }
}

// ---------------- conversions ----------------
// fp32 [M,K] -> bf16 [Mpad,K], padding rows zeroed (Mpad*K multiple of 4)
__global__ void k_cvt_pad(const float* __restrict__ X, unsigned short* __restrict__ Y,
                          int M, int Mpad, int K){
  int idx = blockIdx.x * blockDim.x + threadIdx.x;
  int total = (Mpad * K) >> 2;
  if (idx >= total) return;
  int e = idx << 2;
  int row = e / K;
  ushort4 o;
  if (row < M){
    float4 v = *(const float4*)(X + (size_t)row * K + (e - row * K));
    o.x = f2bf(v.x); o.y = f2bf(v.y); o.z = f2bf(v.z); o.w = f2bf(v.w);
  } else {
    o.x = o.y = o.z = o.w = 0;
  }
  *(ushort4*)(Y + e) = o;
}

// fp32 W [K,N] -> bf16 Wt [N,K]
__global__ void k_wt(const float* __restrict__ W, unsigned short* __restrict__ Wt,
                     int K, int N){
  int idx = blockIdx.x * blockDim.x + threadIdx.x;
  if (idx >= K * N) return;
  int k = idx / N, n = idx - k * N;
  Wt[(size_t)n * K + k] = f2bf(W[idx]);
}

// ---------------- bf16 MFMA GEMM: C[M,N] = A[Mpad,K] @ Bt[N,K]^T (+bias) ----------
typedef __attribute__((ext_vector_type(8))) short bf8_t;
typedef __attribute__((ext_vector_type(4))) float f4_t;

__device__ __forceinline__ void async16(const unsigned short* g, unsigned short* l){
  __builtin_amdgcn_global_load_lds(
      (const __attribute__((address_space(1))) void*)g,
      (__attribute__((address_space(3))) void*)l, 16, 0, 0);
}

__global__ __launch_bounds__(256) void k_mfma_gemm(
    const unsigned short* __restrict__ A,    // [Mpad, K] bf16
    const unsigned short* __restrict__ Bt,   // [N, K] bf16
    const float* __restrict__ bias,          // [N] or nullptr
    void* __restrict__ Cout,                 // [M, N] fp32 or bf16
    int M, int N, int K, int outBf16)
{
  __shared__ unsigned short Asm[128 * 32];
  __shared__ unsigned short Bsm[128 * 32];
  int t = threadIdx.x;
  int w = t >> 6, lane = t & 63;
  int bm = blockIdx.x * 128, bn = blockIdx.y * 128;
  int wm = (w >> 1) * 64, wn = (w & 1) * 64;
  int lr = lane & 15, lq = lane >> 4;

  f4_t acc[4][4] = {};

  int srow = lane >> 2;           // 0..15 within 16-row chunk
  int skc  = (lane & 3) << 3;     // k-chunk offset (0,8,16,24)

  for (int k0 = 0; k0 < K; k0 += 32){
#pragma unroll
    for (int r = 0; r < 2; r++){
      int c = r * 4 + w;          // 16-row chunk index 0..7
      async16(A + (size_t)(bm + c * 16 + srow) * K + k0 + skc, &Asm[c * 512]);
    }
#pragma unroll
    for (int r = 0; r < 2; r++){
      int c = r * 4 + w;
      async16(Bt + (size_t)(bn + c * 16 + srow) * K + k0 + skc, &Bsm[c * 512]);
    }
    __syncthreads();
    bf8_t a[4], b[4];
#pragma unroll
    for (int i = 0; i < 4; i++)
      a[i] = *(const bf8_t*)&Asm[(wm + i * 16 + lr) * 32 + lq * 8];
#pragma unroll
    for (int i = 0; i < 4; i++)
      b[i] = *(const bf8_t*)&Bsm[(wn + i * 16 + lr) * 32 + lq * 8];
#pragma unroll
    for (int mi = 0; mi < 4; mi++)
#pragma unroll
      for (int ni = 0; ni < 4; ni++)
        acc[mi][ni] = __builtin_amdgcn_mfma_f32_16x16x32_bf16(a[mi], b[ni], acc[mi][ni], 0, 0, 0);
    __syncthreads();
  }

#pragma unroll
  for (int mi = 0; mi < 4; mi++){
#pragma unroll
    for (int ni = 0; ni < 4; ni++){
      int colg = bn + wn + ni * 16 + lr;
      float bv = bias ? bias[colg] : 0.f;
#pragma unroll
      for (int rg = 0; rg < 4; rg++){
        int rowg = bm + wm + mi * 16 + lq * 4 + rg;
        if (rowg < M){
          float v = acc[mi][ni][rg] + bv;
          if (outBf16) ((unsigned short*)Cout)[(size_t)rowg * N + colg] = f2bf(v);
          else ((float*)Cout)[(size_t)rowg * N + colg] = v;
        }
      }
    }
  }
}

// ---------------- fp32 tiled GEMM (layer-3 small N) ----------------
#define BM 64
#define BN 64
#define BK 16

__global__ __launch_bounds__(256) void k_gemm(const float* __restrict__ A,
                                              const float* __restrict__ B,
                                              const float* __restrict__ bias,
                                              float* __restrict__ C,
                                              int M, int N, int K){
  __shared__ float As[BK][BM];
  __shared__ float Bs[BK][BN + 4];
  int t  = threadIdx.x;
  int bm = blockIdx.x * BM;
  int bn = blockIdx.y * BN;
  int tx = t & 15, ty = t >> 4;
  float acc[4][4] = {};
  int ar = t >> 2;
  int ak = (t & 3) << 2;
  int br = t >> 4;
  int bc = (t & 15) << 2;
  bool nvec = ((N & 3) == 0);
  for (int k0 = 0; k0 < K; k0 += BK){
    float4 av = {0, 0, 0, 0};
    int arow = bm + ar;
    if (arow < M) av = *(const float4*)(A + (size_t)arow * K + (k0 + ak));
    As[ak + 0][ar] = av.x; As[ak + 1][ar] = av.y;
    As[ak + 2][ar] = av.z; As[ak + 3][ar] = av.w;
    int brow = k0 + br;
    int bcol = bn + bc;
    float4 bv = {0, 0, 0, 0};
    if (nvec){
      if (bcol < N) bv = *(const float4*)(B + (size_t)brow * N + bcol);
    } else {
      float tmp[4] = {0, 0, 0, 0};
      for (int j = 0; j < 4; j++)
        if (bcol + j < N) tmp[j] = B[(size_t)brow * N + bcol + j];
      bv = make_float4(tmp[0], tmp[1], tmp[2], tmp[3]);
    }
    *(float4*)&Bs[br][bc] = bv;
    __syncthreads();
#pragma unroll
    for (int kk = 0; kk < BK; kk++){
      float a0 = As[kk][ty * 4 + 0], a1 = As[kk][ty * 4 + 1];
      float a2 = As[kk][ty * 4 + 2], a3 = As[kk][ty * 4 + 3];
      float4 b4 = *(float4*)&Bs[kk][tx * 4];
      acc[0][0] += a0 * b4.x; acc[0][1] += a0 * b4.y; acc[0][2] += a0 * b4.z; acc[0][3] += a0 * b4.w;
      acc[1][0] += a1 * b4.x; acc[1][1] += a1 * b4.y; acc[1][2] += a1 * b4.z; acc[1][3] += a1 * b4.w;
      acc[2][0] += a2 * b4.x; acc[2][1] += a2 * b4.y; acc[2][2] += a2 * b4.z; acc[2][3] += a2 * b4.w;
      acc[3][0] += a3 * b4.x; acc[3][1] += a3 * b4.y; acc[3][2] += a3 * b4.z; acc[3][3] += a3 * b4.w;
    }
    __syncthreads();
  }
#pragma unroll
  for (int r = 0; r < 4; r++){
    int row = bm + ty * 4 + r;
    if (row >= M) continue;
#pragma unroll
    for (int c = 0; c < 4; c++){
      int colx = bn + tx * 4 + c;
      if (colx < N){
        float v = acc[r][c];
        if (bias) v += bias[colx];
        C[(size_t)row * N + colx] = v;
      }
    }
  }
}

// ---------------- attention dots (layers 1/2), H in bf16 ----------------
__global__ __launch_bounds__(256) void k_attn_dots(const unsigned short* __restrict__ h,
                                                   const float* __restrict__ a_s,
                                                   const float* __restrict__ a_d,
                                                   float* __restrict__ als,
                                                   float* __restrict__ ald, int N){
  int i = blockIdx.x;
  int t = threadIdx.x;          // wave w handles head w (64 lanes x 4ch)
  float4 hv = loadbf4(h + (size_t)i * 1024 + t * 4);
  float4 sv = ((const float4*)a_s)[t];
  float4 dv = ((const float4*)a_d)[t];
  float ps = hv.x * sv.x + hv.y * sv.y + hv.z * sv.z + hv.w * sv.w;
  float pd = hv.x * dv.x + hv.y * dv.y + hv.z * dv.z + hv.w * dv.w;
#pragma unroll
  for (int off = 32; off >= 1; off >>= 1){
    ps += __shfl_down(ps, off);
    pd += __shfl_down(pd, off);
  }
  if ((t & 63) == 0){
    int w = t >> 6;
    als[i * 4 + w] = ps;
    ald[i * 4 + w] = pd;
  }
}

// ---------------- GAT aggregation (layers 1/2), H in bf16 ----------------
__global__ __launch_bounds__(256) void k_agg(const unsigned short* __restrict__ H,
                                             float* __restrict__ Y,
                                             const float* __restrict__ bias,
                                             const float* __restrict__ als,
                                             const float* __restrict__ ald,
                                             const int* __restrict__ rp,
                                             const int* __restrict__ col, int doElu){
  int i = blockIdx.x;
  int t = threadIdx.x;
  int lane = t & 63;
  int w = t >> 6;
  int ro = rp[i];
  int deg = rp[i + 1] - ro;
  __shared__ float sm[4], ss[4];
  __shared__ float s_alpha[64][4];
  __shared__ int s_src[64];

  // phase 1: per-head online softmax over incoming edges + self loop
  float aldw = ald[i * 4 + w];
  float eself = leaky(als[i * 4 + w] + aldw);
  float m = eself;
  float s = (lane == 0) ? 1.f : 0.f;
  for (int e = lane; e < deg; e += 64){
    int src = col[ro + e];
    float ev = leaky(als[src * 4 + w] + aldw);
    float M = fmaxf(m, ev);
    s = s * __expf(m - M) + __expf(ev - M);
    m = M;
  }
#pragma unroll
  for (int off = 32; off >= 1; off >>= 1){
    float mo = __shfl_down(m, off);
    float so = __shfl_down(s, off);
    float M = fmaxf(m, mo);
    s = s * __expf(m - M) + so * __expf(mo - M);
    m = M;
  }
  if (lane == 0){ sm[w] = m; ss[w] = s; }
  __syncthreads();

  // phase 2: thread t owns channels 4t..4t+3 (head = t>>6)
  int head = t >> 6;
  float mh = sm[head];
  float inv = 1.f / (ss[head] + 1e-16f);
  float4 acc = *(const float4*)(Y + (size_t)i * 1024 + t * 4);
  float4 bb  = *(const float4*)(bias + t * 4);
  acc.x += bb.x; acc.y += bb.y; acc.z += bb.z; acc.w += bb.w;
  float aself = __expf(leaky(als[i * 4 + head] + ald[i * 4 + head]) - mh) * inv;
  {
    float4 hv = loadbf4(H + (size_t)i * 1024 + t * 4);
    acc.x += aself * hv.x; acc.y += aself * hv.y;
    acc.z += aself * hv.z; acc.w += aself * hv.w;
  }
  for (int base = 0; base < deg; base += 64){
    __syncthreads();
    if (t < 64 && base + t < deg){
      int src = col[ro + base + t];
      s_src[t] = src;
#pragma unroll
      for (int hh = 0; hh < 4; hh++){
        s_alpha[t][hh] = __expf(leaky(als[src * 4 + hh] + ald[i * 4 + hh]) - sm[hh])
                         / (ss[hh] + 1e-16f);
      }
    }
    __syncthreads();
    int nn = min(64, deg - base);
    for (int e = 0; e < nn; e++){
      float a = s_alpha[e][head];
      float4 hv = loadbf4(H + (size_t)s_src[e] * 1024 + t * 4);
      acc.x += a * hv.x; acc.y += a * hv.y; acc.z += a * hv.z; acc.w += a * hv.w;
    }
  }
  if (doElu){
    acc.x = acc.x > 0.f ? acc.x : expm1f(acc.x);
    acc.y = acc.y > 0.f ? acc.y : expm1f(acc.y);
    acc.z = acc.z > 0.f ? acc.z : expm1f(acc.z);
    acc.w = acc.w > 0.f ? acc.w : expm1f(acc.w);
  }
  *(float4*)(Y + (size_t)i * 1024 + t * 4) = acc;
}

// ---------------- layer-3 attention dots ----------------
__global__ void k_attn3(const float* __restrict__ h3, const float* __restrict__ a_s,
                        const float* __restrict__ a_d, float* __restrict__ als,
                        float* __restrict__ ald, int N){
  int i = blockIdx.x * blockDim.x + threadIdx.x;
  if (i >= N) return;
  const float* hp = h3 + (size_t)i * 36;
#pragma unroll
  for (int hh = 0; hh < 6; hh++){
    float s = 0.f, d = 0.f;
#pragma unroll
    for (int c = 0; c < 6; c++){
      float v = hp[hh * 6 + c];
      s += v * a_s[hh * 6 + c];
      d += v * a_d[hh * 6 + c];
    }
    als[i * 6 + hh] = s;
    ald[i * 6 + hh] = d;
  }
}

// ---------------- layer 3: GAT(mean heads) + b3 + lin3 + log_softmax ----------------
__global__ __launch_bounds__(64) void k_layer3(const float* __restrict__ h3,
                                               const float* __restrict__ lin3,
                                               const float* __restrict__ als,
                                               const float* __restrict__ ald,
                                               const float* __restrict__ b3,
                                               const int* __restrict__ rp,
                                               const int* __restrict__ col,
                                               float* __restrict__ out){
  int i = blockIdx.x;
  int lane = threadIdx.x;
  int ro = rp[i], deg = rp[i + 1] - ro;
  float aldv[6], m[6], s[6];
#pragma unroll
  for (int h = 0; h < 6; h++){
    aldv[h] = ald[i * 6 + h];
    float e = leaky(als[i * 6 + h] + aldv[h]);
    m[h] = e;
    s[h] = (lane == 0) ? 1.f : 0.f;
  }
  for (int e = lane; e < deg; e += 64){
    int src = col[ro + e];
#pragma unroll
    for (int h = 0; h < 6; h++){
      float ev = leaky(als[src * 6 + h] + aldv[h]);
      float M = fmaxf(m[h], ev);
      s[h] = s[h] * __expf(m[h] - M) + __expf(ev - M);
      m[h] = M;
    }
  }
#pragma unroll
  for (int off = 32; off >= 1; off >>= 1){
#pragma unroll
    for (int h = 0; h < 6; h++){
      float mo = __shfl_down(m[h], off);
      float so = __shfl_down(s[h], off);
      float M = fmaxf(m[h], mo);
      s[h] = s[h] * __expf(m[h] - M) + so * __expf(mo - M);
      m[h] = M;
    }
  }
#pragma unroll
  for (int h = 0; h < 6; h++){ m[h] = __shfl(m[h], 0); s[h] = __shfl(s[h], 0); }

  __shared__ float o36[36];
  __shared__ float o6[6];
  if (lane < 36){
    int hh = lane / 6, cc = lane - hh * 6;
    float inv = 1.f / (s[hh] + 1e-16f);
    float acc = __expf(leaky(als[i * 6 + hh] + aldv[hh]) - m[hh]) * inv
                * h3[(size_t)i * 36 + hh * 6 + cc];
    for (int e = 0; e < deg; e++){
      int src = col[ro + e];
      float a = __expf(leaky(als[src * 6 + hh] + aldv[hh]) - m[hh]) * inv;
      acc += a * h3[(size_t)src * 36 + hh * 6 + cc];
    }
    o36[lane] = acc;
  }
  __syncthreads();
  if (lane < 6){
    float v = 0.f;
#pragma unroll
    for (int h = 0; h < 6; h++) v += o36[h * 6 + lane];
    o6[lane] = v * (1.f / 6.f) + b3[lane] + lin3[i * 6 + lane];
  }
  __syncthreads();
  if (lane == 0){
    float mx = o6[0];
    for (int c = 1; c < 6; c++) mx = fmaxf(mx, o6[c]);
    float se = 0.f;
    for (int c = 0; c < 6; c++) se += __expf(o6[c] - mx);
    float lse = logf(se);
    for (int c = 0; c < 6; c++) out[(size_t)i * 6 + c] = o6[c] - mx - lse;
  }
}

// ---------------------------------------------------------------------------
extern "C" void kernel_launch(void* const* d_in, const int* in_sizes, int n_in,
                              void* d_out, int out_size, void* d_ws, size_t ws_size,
                              hipStream_t stream){
  const float* nf  = (const float*)d_in[0];
  const int*   ei  = (const int*)d_in[1];
  const float* W1  = (const float*)d_in[2];
  const float* as1 = (const float*)d_in[3];
  const float* ad1 = (const float*)d_in[4];
  const float* b1  = (const float*)d_in[5];
  const float* Wl1 = (const float*)d_in[6];
  const float* bl1 = (const float*)d_in[7];
  const float* W2  = (const float*)d_in[8];
  const float* as2 = (const float*)d_in[9];
  const float* ad2 = (const float*)d_in[10];
  const float* b2  = (const float*)d_in[11];
  const float* Wl2 = (const float*)d_in[12];
  const float* bl2 = (const float*)d_in[13];
  const float* W3  = (const float*)d_in[14];
  const float* as3 = (const float*)d_in[15];
  const float* ad3 = (const float*)d_in[16];
  const float* b3  = (const float*)d_in[17];
  const float* Wl3 = (const float*)d_in[18];
  const float* bl3 = (const float*)d_in[19];
  float* out = (float*)d_out;

  const int N = in_sizes[0] / 512;   // 10000
  const int E = in_sizes[1] / 2;     // 160000
  const int Mpad = ((N + 127) / 128) * 128;   // 10112

  char* ws = (char*)d_ws;
  size_t off = 0;
  auto alloc = [&](size_t bytes) -> char* {
    char* p = ws + off;
    off += (bytes + 255) & ~(size_t)255;
    return p;
  };
  unsigned short* Abf = (unsigned short*)alloc((size_t)Mpad * 1024 * 2);  // GEMM A (bf16)
  unsigned short* Hbf = (unsigned short*)alloc((size_t)N * 1024 * 2);     // attn features
  float* Bb   = (float*)alloc((size_t)N * 1024 * 4);                      // linear path (fp32)
  float* h3   = (float*)alloc((size_t)N * 36 * 4);
  float* lin3 = (float*)alloc((size_t)N * 6 * 4);
  float* als  = (float*)alloc((size_t)N * 8 * 4);
  float* ald  = (float*)alloc((size_t)N * 8 * 4);
  int* deg    = (int*)alloc((size_t)N * 4);
  int* rp     = (int*)alloc((size_t)(N + 1) * 4);
  int* cur    = (int*)alloc((size_t)N * 4);
  int* colx   = (int*)alloc((size_t)E * 4);
  unsigned short* W1t  = (unsigned short*)alloc((size_t)512 * 1024 * 2);   // [1024,512]
  unsigned short* Wl1t = (unsigned short*)alloc((size_t)512 * 1024 * 2);
  unsigned short* W2t  = (unsigned short*)alloc((size_t)1024 * 1024 * 2);  // [1024,1024]
  unsigned short* Wl2t = (unsigned short*)alloc((size_t)1024 * 1024 * 2);

  // CSR build (ws re-poisoned every call)
  hipMemsetAsync(deg, 0, (size_t)N * 4, stream);
  k_count  <<<(E + 255) / 256, 256, 0, stream>>>(ei, deg, E);
  k_scan   <<<1, 1024, 0, stream>>>(deg, rp, N);
  k_cursor <<<(N + 255) / 256, 256, 0, stream>>>(rp, cur, N);
  k_scatter<<<(E + 255) / 256, 256, 0, stream>>>(ei, cur, colx, E);

  // weight conversion + transpose
  k_wt<<<(512 * 1024 + 255) / 256, 256, 0, stream>>>(W1, W1t, 512, 1024);
  k_wt<<<(512 * 1024 + 255) / 256, 256, 0, stream>>>(Wl1, Wl1t, 512, 1024);
  k_wt<<<(1024 * 1024 + 255) / 256, 256, 0, stream>>>(W2, W2t, 1024, 1024);
  k_wt<<<(1024 * 1024 + 255) / 256, 256, 0, stream>>>(Wl2, Wl2t, 1024, 1024);

  dim3 gg(Mpad / 128, 1024 / 128);

  // layer 1
  k_cvt_pad<<<(Mpad * 512 / 4 + 255) / 256, 256, 0, stream>>>(nf, Abf, N, Mpad, 512);
  k_mfma_gemm<<<gg, 256, 0, stream>>>(Abf, W1t, nullptr, Hbf, N, 1024, 512, 1);
  k_mfma_gemm<<<gg, 256, 0, stream>>>(Abf, Wl1t, bl1, Bb, N, 1024, 512, 0);
  k_attn_dots<<<N, 256, 0, stream>>>(Hbf, as1, ad1, als, ald, N);
  k_agg<<<N, 256, 0, stream>>>(Hbf, Bb, b1, als, ald, rp, colx, 1);

  // layer 2
  k_cvt_pad<<<(Mpad * 1024 / 4 + 255) / 256, 256, 0, stream>>>(Bb, Abf, N, Mpad, 1024);
  k_mfma_gemm<<<gg, 256, 0, stream>>>(Abf, W2t, nullptr, Hbf, N, 1024, 1024, 1);
  k_mfma_gemm<<<gg, 256, 0, stream>>>(Abf, Wl2t, bl2, Bb, N, 1024, 1024, 0);
  k_attn_dots<<<N, 256, 0, stream>>>(Hbf, as2, ad2, als, ald, N);
  k_agg<<<N, 256, 0, stream>>>(Hbf, Bb, b2, als, ald, rp, colx, 1);

  // layer 3 (small, fp32)
  dim3 g3((N + 63) / 64, 1);
  k_gemm<<<g3, 256, 0, stream>>>(Bb, W3, nullptr, h3, N, 36, 1024);
  k_gemm<<<g3, 256, 0, stream>>>(Bb, Wl3, bl3, lin3, N, 6, 1024);
  k_attn3<<<(N + 255) / 256, 256, 0, stream>>>(h3, as3, ad3, als, ald, N);
  k_layer3<<<N, 64, 0, stream>>>(h3, lin3, als, ald, b3, rp, colx, out);
}

// Round 3
// 504.900 us; speedup vs baseline: 2.7884x; 1.2218x over previous
//
#include <hip/hip_runtime.h>
#include <math.h>

// ---------------------------------------------------------------------------
// GAT 3-layer net. R3:
//  - layers 1/2: ONE fused bf16 MFMA GEMM per layer (N=2048, split epilogue:
//    cols<1024 -> Hbf bf16 attn features, cols>=1024 -> Bb fp32 + bias)
//  - layer 3: bf16 MFMA GEMM over combined [W3|Wl3] (42 cols, pad 48/128)
//  - LDS-tiled coalesced weight transpose (fp32 [K,N] -> bf16 [N,K])
// ---------------------------------------------------------------------------

__device__ __forceinline__ float leaky(float x){ return x > 0.f ? x : 0.2f * x; }

__device__ __forceinline__ float bf2f(unsigned short u){
  union { unsigned int i; float f; } v; v.i = ((unsigned int)u) << 16; return v.f;
}
__device__ __forceinline__ unsigned short f2bf(float f){
  union { float f; unsigned int i; } v; v.f = f;
  unsigned int r = v.i + 0x7FFF + ((v.i >> 16) & 1);   // RNE
  return (unsigned short)(r >> 16);
}
__device__ __forceinline__ float4 loadbf4(const unsigned short* p){
  ushort4 u = *(const ushort4*)p;
  return make_float4(bf2f(u.x), bf2f(u.y), bf2f(u.z), bf2f(u.w));
}

// ---------------- CSR build ----------------
__global__ void k_count(const int* __restrict__ ei, int* __restrict__ deg, int E){
  int e = blockIdx.x * blockDim.x + threadIdx.x;
  if (e < E) atomicAdd(&deg[ei[E + e]], 1);
}

__global__ void k_scan(const int* __restrict__ deg, int* __restrict__ rp,
                       int* __restrict__ cur, int n){
  __shared__ int part[1024];
  int t = threadIdx.x;
  int K = (n + 1023) >> 10;
  int vals[16];
  int start = t * K;
  int local = 0;
  for (int j = 0; j < K; j++){
    int idx = start + j;
    int v = (idx < n) ? deg[idx] : 0;
    vals[j] = local;
    local += v;
  }
  part[t] = local;
  __syncthreads();
  for (int off = 1; off < 1024; off <<= 1){
    int v = (t >= off) ? part[t - off] : 0;
    __syncthreads();
    part[t] += v;
    __syncthreads();
  }
  int base = part[t] - local;
  for (int j = 0; j < K; j++){
    int idx = start + j;
    if (idx < n){ rp[idx] = base + vals[j]; cur[idx] = base + vals[j]; }
  }
  if (t == 1023) rp[n] = part[1023];
}

__global__ void k_scatter(const int* __restrict__ ei, int* __restrict__ cur,
                          int* __restrict__ col, int E){
  int e = blockIdx.x * blockDim.x + threadIdx.x;
  if (e < E){
    int s = ei[e], d = ei[E + e];
    int p = atomicAdd(&cur[d], 1);
    col[p] = s;
  }
}

// ---------------- conversions ----------------
// fp32 [M,K] -> bf16 [Mpad,K], padding rows zeroed
__global__ void k_cvt_pad(const float* __restrict__ X, unsigned short* __restrict__ Y,
                          int M, int Mpad, int K){
  int idx = blockIdx.x * blockDim.x + threadIdx.x;
  int total = (Mpad * K) >> 2;
  if (idx >= total) return;
  int e = idx << 2;
  int row = e / K;
  ushort4 o;
  if (row < M){
    float4 v = *(const float4*)(X + (size_t)row * K + (e - row * K));
    o.x = f2bf(v.x); o.y = f2bf(v.y); o.z = f2bf(v.z); o.w = f2bf(v.w);
  } else {
    o.x = o.y = o.z = o.w = 0;
  }
  *(ushort4*)(Y + e) = o;
}

// LDS-tiled transpose: fp32 W[K,N] -> bf16 Wt rows [rowOff+n][k]. K,N mult of 32.
__global__ __launch_bounds__(256) void k_tr32(const float* __restrict__ W,
                                              unsigned short* __restrict__ Wt,
                                              int K, int N, int rowOff){
  __shared__ unsigned short tile[32][33];
  int bk = blockIdx.x * 32;
  int bn = blockIdx.y * 32;
  int tx = threadIdx.x & 31;
  int ty = threadIdx.x >> 5;          // 0..7
#pragma unroll
  for (int r = 0; r < 32; r += 8)
    tile[ty + r][tx] = f2bf(W[(size_t)(bk + ty + r) * N + bn + tx]);
  __syncthreads();
#pragma unroll
  for (int r = 0; r < 32; r += 8)
    Wt[(size_t)(rowOff + bn + ty + r) * K + bk + tx] = tile[tx][ty + r];
}

// layer-3 combined weights: Bt[128][K] bf16 (rows 0-35 W3^T, 36-41 Wl3^T, rest 0)
// and biasc[48] (0-35 zero, 36-41 bl3)
__global__ void k_w3fill(const float* __restrict__ W3, const float* __restrict__ Wl3,
                         const float* __restrict__ bl3, unsigned short* __restrict__ Bt,
                         float* __restrict__ biasc, int K){
  int idx = blockIdx.x * blockDim.x + threadIdx.x;
  if (idx < 48) biasc[idx] = (idx >= 36 && idx < 42) ? bl3[idx - 36] : 0.f;
  if (idx >= 128 * K) return;
  int n = idx / K, k = idx - n * K;
  float v = 0.f;
  if (n < 36) v = W3[(size_t)k * 36 + n];
  else if (n < 42) v = Wl3[(size_t)k * 6 + (n - 36)];
  Bt[idx] = f2bf(v);
}

// ---------------- bf16 MFMA GEMM with split epilogue ----------------
typedef __attribute__((ext_vector_type(8))) short bf8_t;
typedef __attribute__((ext_vector_type(4))) float f4_t;

__device__ __forceinline__ void async16(const unsigned short* g, unsigned short* l){
  __builtin_amdgcn_global_load_lds(
      (const __attribute__((address_space(1))) void*)g,
      (__attribute__((address_space(3))) void*)l, 16, 0, 0);
}

// C[M, Ntot] = A[Mpad,K] @ Bt[Npad,K]^T; cols<split -> outBf (bf16, stride=split),
// cols in [split,Ntot) -> outF (fp32, stride=Ntot-split) + bias[col-split]
__global__ __launch_bounds__(256) void k_mfma_gemm(
    const unsigned short* __restrict__ A,
    const unsigned short* __restrict__ Bt,
    const float* __restrict__ bias,
    unsigned short* __restrict__ outBf,
    float* __restrict__ outF,
    int M, int K, int Ntot, int split)
{
  __shared__ unsigned short Asm[128 * 32];
  __shared__ unsigned short Bsm[128 * 32];
  int t = threadIdx.x;
  int w = t >> 6, lane = t & 63;
  int bm = blockIdx.x * 128, bn = blockIdx.y * 128;
  int wm = (w >> 1) * 64, wn = (w & 1) * 64;
  int lr = lane & 15, lq = lane >> 4;

  f4_t acc[4][4] = {};

  int srow = lane >> 2;
  int skc  = (lane & 3) << 3;

  for (int k0 = 0; k0 < K; k0 += 32){
#pragma unroll
    for (int r = 0; r < 2; r++){
      int c = r * 4 + w;
      async16(A + (size_t)(bm + c * 16 + srow) * K + k0 + skc, &Asm[c * 512]);
    }
#pragma unroll
    for (int r = 0; r < 2; r++){
      int c = r * 4 + w;
      async16(Bt + (size_t)(bn + c * 16 + srow) * K + k0 + skc, &Bsm[c * 512]);
    }
    __syncthreads();
    bf8_t a[4], b[4];
#pragma unroll
    for (int i = 0; i < 4; i++)
      a[i] = *(const bf8_t*)&Asm[(wm + i * 16 + lr) * 32 + lq * 8];
#pragma unroll
    for (int i = 0; i < 4; i++)
      b[i] = *(const bf8_t*)&Bsm[(wn + i * 16 + lr) * 32 + lq * 8];
#pragma unroll
    for (int mi = 0; mi < 4; mi++)
#pragma unroll
      for (int ni = 0; ni < 4; ni++)
        acc[mi][ni] = __builtin_amdgcn_mfma_f32_16x16x32_bf16(a[mi], b[ni], acc[mi][ni], 0, 0, 0);
    __syncthreads();
  }

  int strideF = Ntot - split;
#pragma unroll
  for (int mi = 0; mi < 4; mi++){
#pragma unroll
    for (int ni = 0; ni < 4; ni++){
      int colg = bn + wn + ni * 16 + lr;
      if (colg >= Ntot) continue;
      bool isF = (colg >= split);
      float bv = isF ? bias[colg - split] : 0.f;
#pragma unroll
      for (int rg = 0; rg < 4; rg++){
        int rowg = bm + wm + mi * 16 + lq * 4 + rg;
        if (rowg < M){
          float v = acc[mi][ni][rg] + bv;
          if (isF) outF[(size_t)rowg * strideF + (colg - split)] = v;
          else outBf[(size_t)rowg * split + colg] = f2bf(v);
        }
      }
    }
  }
}

// ---------------- attention dots (layers 1/2), H in bf16 ----------------
__global__ __launch_bounds__(256) void k_attn_dots(const unsigned short* __restrict__ h,
                                                   const float* __restrict__ a_s,
                                                   const float* __restrict__ a_d,
                                                   float* __restrict__ als,
                                                   float* __restrict__ ald, int N){
  int i = blockIdx.x;
  int t = threadIdx.x;
  float4 hv = loadbf4(h + (size_t)i * 1024 + t * 4);
  float4 sv = ((const float4*)a_s)[t];
  float4 dv = ((const float4*)a_d)[t];
  float ps = hv.x * sv.x + hv.y * sv.y + hv.z * sv.z + hv.w * sv.w;
  float pd = hv.x * dv.x + hv.y * dv.y + hv.z * dv.z + hv.w * dv.w;
#pragma unroll
  for (int off = 32; off >= 1; off >>= 1){
    ps += __shfl_down(ps, off);
    pd += __shfl_down(pd, off);
  }
  if ((t & 63) == 0){
    int w = t >> 6;
    als[i * 4 + w] = ps;
    ald[i * 4 + w] = pd;
  }
}

// ---------------- GAT aggregation (layers 1/2), H in bf16 ----------------
__global__ __launch_bounds__(256) void k_agg(const unsigned short* __restrict__ H,
                                             float* __restrict__ Y,
                                             const float* __restrict__ bias,
                                             const float* __restrict__ als,
                                             const float* __restrict__ ald,
                                             const int* __restrict__ rp,
                                             const int* __restrict__ col, int doElu){
  int i = blockIdx.x;
  int t = threadIdx.x;
  int lane = t & 63;
  int w = t >> 6;
  int ro = rp[i];
  int deg = rp[i + 1] - ro;
  __shared__ float sm[4], ss[4];
  __shared__ float s_alpha[64][4];
  __shared__ int s_src[64];

  float aldw = ald[i * 4 + w];
  float eself = leaky(als[i * 4 + w] + aldw);
  float m = eself;
  float s = (lane == 0) ? 1.f : 0.f;
  for (int e = lane; e < deg; e += 64){
    int src = col[ro + e];
    float ev = leaky(als[src * 4 + w] + aldw);
    float M = fmaxf(m, ev);
    s = s * __expf(m - M) + __expf(ev - M);
    m = M;
  }
#pragma unroll
  for (int off = 32; off >= 1; off >>= 1){
    float mo = __shfl_down(m, off);
    float so = __shfl_down(s, off);
    float M = fmaxf(m, mo);
    s = s * __expf(m - M) + so * __expf(mo - M);
    m = M;
  }
  if (lane == 0){ sm[w] = m; ss[w] = s; }
  __syncthreads();

  int head = t >> 6;
  float mh = sm[head];
  float inv = 1.f / (ss[head] + 1e-16f);
  float4 acc = *(const float4*)(Y + (size_t)i * 1024 + t * 4);
  float4 bb  = *(const float4*)(bias + t * 4);
  acc.x += bb.x; acc.y += bb.y; acc.z += bb.z; acc.w += bb.w;
  float aself = __expf(leaky(als[i * 4 + head] + ald[i * 4 + head]) - mh) * inv;
  {
    float4 hv = loadbf4(H + (size_t)i * 1024 + t * 4);
    acc.x += aself * hv.x; acc.y += aself * hv.y;
    acc.z += aself * hv.z; acc.w += aself * hv.w;
  }
  for (int base = 0; base < deg; base += 64){
    __syncthreads();
    if (t < 64 && base + t < deg){
      int src = col[ro + base + t];
      s_src[t] = src;
#pragma unroll
      for (int hh = 0; hh < 4; hh++){
        s_alpha[t][hh] = __expf(leaky(als[src * 4 + hh] + ald[i * 4 + hh]) - sm[hh])
                         / (ss[hh] + 1e-16f);
      }
    }
    __syncthreads();
    int nn = min(64, deg - base);
    for (int e = 0; e < nn; e++){
      float a = s_alpha[e][head];
      float4 hv = loadbf4(H + (size_t)s_src[e] * 1024 + t * 4);
      acc.x += a * hv.x; acc.y += a * hv.y; acc.z += a * hv.z; acc.w += a * hv.w;
    }
  }
  if (doElu){
    acc.x = acc.x > 0.f ? acc.x : expm1f(acc.x);
    acc.y = acc.y > 0.f ? acc.y : expm1f(acc.y);
    acc.z = acc.z > 0.f ? acc.z : expm1f(acc.z);
    acc.w = acc.w > 0.f ? acc.w : expm1f(acc.w);
  }
  *(float4*)(Y + (size_t)i * 1024 + t * 4) = acc;
}

// ---------------- layer-3 attention dots (comb stride 48) ----------------
__global__ void k_attn3(const float* __restrict__ comb, const float* __restrict__ a_s,
                        const float* __restrict__ a_d, float* __restrict__ als,
                        float* __restrict__ ald, int N){
  int i = blockIdx.x * blockDim.x + threadIdx.x;
  if (i >= N) return;
  const float* hp = comb + (size_t)i * 48;
#pragma unroll
  for (int hh = 0; hh < 6; hh++){
    float s = 0.f, d = 0.f;
#pragma unroll
    for (int c = 0; c < 6; c++){
      float v = hp[hh * 6 + c];
      s += v * a_s[hh * 6 + c];
      d += v * a_d[hh * 6 + c];
    }
    als[i * 6 + hh] = s;
    ald[i * 6 + hh] = d;
  }
}

// ---------------- layer 3: GAT(mean heads) + b3 + lin3 + log_softmax ----------------
__global__ __launch_bounds__(64) void k_layer3(const float* __restrict__ comb,
                                               const float* __restrict__ als,
                                               const float* __restrict__ ald,
                                               const float* __restrict__ b3,
                                               const int* __restrict__ rp,
                                               const int* __restrict__ col,
                                               float* __restrict__ out){
  int i = blockIdx.x;
  int lane = threadIdx.x;
  int ro = rp[i], deg = rp[i + 1] - ro;
  float aldv[6], m[6], s[6];
#pragma unroll
  for (int h = 0; h < 6; h++){
    aldv[h] = ald[i * 6 + h];
    float e = leaky(als[i * 6 + h] + aldv[h]);
    m[h] = e;
    s[h] = (lane == 0) ? 1.f : 0.f;
  }
  for (int e = lane; e < deg; e += 64){
    int src = col[ro + e];
#pragma unroll
    for (int h = 0; h < 6; h++){
      float ev = leaky(als[src * 6 + h] + aldv[h]);
      float M = fmaxf(m[h], ev);
      s[h] = s[h] * __expf(m[h] - M) + __expf(ev - M);
      m[h] = M;
    }
  }
#pragma unroll
  for (int off = 32; off >= 1; off >>= 1){
#pragma unroll
    for (int h = 0; h < 6; h++){
      float mo = __shfl_down(m[h], off);
      float so = __shfl_down(s[h], off);
      float M = fmaxf(m[h], mo);
      s[h] = s[h] * __expf(m[h] - M) + so * __expf(mo - M);
      m[h] = M;
    }
  }
#pragma unroll
  for (int h = 0; h < 6; h++){ m[h] = __shfl(m[h], 0); s[h] = __shfl(s[h], 0); }

  __shared__ float o36[36];
  __shared__ float o6[6];
  if (lane < 36){
    int hh = lane / 6, cc = lane - hh * 6;
    float inv = 1.f / (s[hh] + 1e-16f);
    float acc = __expf(leaky(als[i * 6 + hh] + aldv[hh]) - m[hh]) * inv
                * comb[(size_t)i * 48 + hh * 6 + cc];
    for (int e = 0; e < deg; e++){
      int src = col[ro + e];
      float a = __expf(leaky(als[src * 6 + hh] + aldv[hh]) - m[hh]) * inv;
      acc += a * comb[(size_t)src * 48 + hh * 6 + cc];
    }
    o36[lane] = acc;
  }
  __syncthreads();
  if (lane < 6){
    float v = 0.f;
#pragma unroll
    for (int h = 0; h < 6; h++) v += o36[h * 6 + lane];
    o6[lane] = v * (1.f / 6.f) + b3[lane] + comb[(size_t)i * 48 + 36 + lane];
  }
  __syncthreads();
  if (lane == 0){
    float mx = o6[0];
    for (int c = 1; c < 6; c++) mx = fmaxf(mx, o6[c]);
    float se = 0.f;
    for (int c = 0; c < 6; c++) se += __expf(o6[c] - mx);
    float lse = logf(se);
    for (int c = 0; c < 6; c++) out[(size_t)i * 6 + c] = o6[c] - mx - lse;
  }
}

// ---------------------------------------------------------------------------
extern "C" void kernel_launch(void* const* d_in, const int* in_sizes, int n_in,
                              void* d_out, int out_size, void* d_ws, size_t ws_size,
                              hipStream_t stream){
  const float* nf  = (const float*)d_in[0];
  const int*   ei  = (const int*)d_in[1];
  const float* W1  = (const float*)d_in[2];
  const float* as1 = (const float*)d_in[3];
  const float* ad1 = (const float*)d_in[4];
  const float* b1  = (const float*)d_in[5];
  const float* Wl1 = (const float*)d_in[6];
  const float* bl1 = (const float*)d_in[7];
  const float* W2  = (const float*)d_in[8];
  const float* as2 = (const float*)d_in[9];
  const float* ad2 = (const float*)d_in[10];
  const float* b2  = (const float*)d_in[11];
  const float* Wl2 = (const float*)d_in[12];
  const float* bl2 = (const float*)d_in[13];
  const float* W3  = (const float*)d_in[14];
  const float* as3 = (const float*)d_in[15];
  const float* ad3 = (const float*)d_in[16];
  const float* b3  = (const float*)d_in[17];
  const float* Wl3 = (const float*)d_in[18];
  const float* bl3 = (const float*)d_in[19];
  float* out = (float*)d_out;

  const int N = in_sizes[0] / 512;   // 10000
  const int E = in_sizes[1] / 2;     // 160000
  const int Mpad = ((N + 127) / 128) * 128;   // 10112

  char* ws = (char*)d_ws;
  size_t off = 0;
  auto alloc = [&](size_t bytes) -> char* {
    char* p = ws + off;
    off += (bytes + 255) & ~(size_t)255;
    return p;
  };
  unsigned short* Abf  = (unsigned short*)alloc((size_t)Mpad * 1024 * 2); // GEMM A bf16
  unsigned short* Hbf  = (unsigned short*)alloc((size_t)N * 1024 * 2);    // attn features
  float* Bb    = (float*)alloc((size_t)N * 1024 * 4);                     // linear path fp32
  float* comb  = (float*)alloc((size_t)N * 48 * 4);                       // layer-3 [h3|lin3]
  float* als   = (float*)alloc((size_t)N * 8 * 4);
  float* ald   = (float*)alloc((size_t)N * 8 * 4);
  float* biasc = (float*)alloc(48 * 4);
  int* deg     = (int*)alloc((size_t)N * 4);
  int* rp      = (int*)alloc((size_t)(N + 1) * 4);
  int* cur     = (int*)alloc((size_t)N * 4);
  int* colx    = (int*)alloc((size_t)E * 4);
  unsigned short* Wc1 = (unsigned short*)alloc((size_t)2048 * 512 * 2);   // [2048,512]
  unsigned short* Wc2 = (unsigned short*)alloc((size_t)2048 * 1024 * 2);  // [2048,1024]
  unsigned short* Bt3 = (unsigned short*)alloc((size_t)128 * 1024 * 2);   // [128,1024]

  // CSR build
  hipMemsetAsync(deg, 0, (size_t)N * 4, stream);
  k_count  <<<(E + 255) / 256, 256, 0, stream>>>(ei, deg, E);
  k_scan   <<<1, 1024, 0, stream>>>(deg, rp, cur, N);
  k_scatter<<<(E + 255) / 256, 256, 0, stream>>>(ei, cur, colx, E);

  // weight prep
  k_tr32<<<dim3(512 / 32, 1024 / 32), 256, 0, stream>>>(W1, Wc1, 512, 1024, 0);
  k_tr32<<<dim3(512 / 32, 1024 / 32), 256, 0, stream>>>(Wl1, Wc1, 512, 1024, 1024);
  k_tr32<<<dim3(1024 / 32, 1024 / 32), 256, 0, stream>>>(W2, Wc2, 1024, 1024, 0);
  k_tr32<<<dim3(1024 / 32, 1024 / 32), 256, 0, stream>>>(Wl2, Wc2, 1024, 1024, 1024);
  k_w3fill<<<(128 * 1024 + 255) / 256, 256, 0, stream>>>(W3, Wl3, bl3, Bt3, biasc, 1024);

  dim3 ggL(Mpad / 128, 16);   // N=2048
  dim3 gg3(Mpad / 128, 1);

  // layer 1
  k_cvt_pad<<<(Mpad * 512 / 4 + 255) / 256, 256, 0, stream>>>(nf, Abf, N, Mpad, 512);
  k_mfma_gemm<<<ggL, 256, 0, stream>>>(Abf, Wc1, bl1, Hbf, Bb, N, 512, 2048, 1024);
  k_attn_dots<<<N, 256, 0, stream>>>(Hbf, as1, ad1, als, ald, N);
  k_agg<<<N, 256, 0, stream>>>(Hbf, Bb, b1, als, ald, rp, colx, 1);

  // layer 2
  k_cvt_pad<<<(Mpad * 1024 / 4 + 255) / 256, 256, 0, stream>>>(Bb, Abf, N, Mpad, 1024);
  k_mfma_gemm<<<ggL, 256, 0, stream>>>(Abf, Wc2, bl2, Hbf, Bb, N, 1024, 2048, 1024);
  k_attn_dots<<<N, 256, 0, stream>>>(Hbf, as2, ad2, als, ald, N);
  k_agg<<<N, 256, 0, stream>>>(Hbf, Bb, b2, als, ald, rp, colx, 1);

  // layer 3
  k_cvt_pad<<<(Mpad * 1024 / 4 + 255) / 256, 256, 0, stream>>>(Bb, Abf, N, Mpad, 1024);
  k_mfma_gemm<<<gg3, 256, 0, stream>>>(Abf, Bt3, biasc, nullptr, comb, N, 1024, 48, 0);
  k_attn3<<<(N + 255) / 256, 256, 0, stream>>>(comb, as3, ad3, als, ald, N);
  k_layer3<<<N, 64, 0, stream>>>(comb, als, ald, b3, rp, colx, out);
}

// Round 4
// 457.364 us; speedup vs baseline: 3.0782x; 1.1039x over previous
//
#include <hip/hip_runtime.h>
#include <math.h>

// ---------------------------------------------------------------------------
// GAT 3-layer net. R4:
//  - k_mfma_gemm: 1D XCD-aware swizzled grid (xcd = b&7 owns ~Mtiles/8 m-tiles
//    across all n-tiles) so each XCD's A working set (~2.6 MB) stays in its L2.
//  - k_agg writes bf16 directly into next layer's GEMM-A buffer (no cvt_pad
//    for layers 2/3); pad rows zeroed once via hipMemsetAsync.
// ---------------------------------------------------------------------------

__device__ __forceinline__ float leaky(float x){ return x > 0.f ? x : 0.2f * x; }

__device__ __forceinline__ float bf2f(unsigned short u){
  union { unsigned int i; float f; } v; v.i = ((unsigned int)u) << 16; return v.f;
}
__device__ __forceinline__ unsigned short f2bf(float f){
  union { float f; unsigned int i; } v; v.f = f;
  unsigned int r = v.i + 0x7FFF + ((v.i >> 16) & 1);   // RNE
  return (unsigned short)(r >> 16);
}
__device__ __forceinline__ float4 loadbf4(const unsigned short* p){
  ushort4 u = *(const ushort4*)p;
  return make_float4(bf2f(u.x), bf2f(u.y), bf2f(u.z), bf2f(u.w));
}

// ---------------- CSR build ----------------
__global__ void k_count(const int* __restrict__ ei, int* __restrict__ deg, int E){
  int e = blockIdx.x * blockDim.x + threadIdx.x;
  if (e < E) atomicAdd(&deg[ei[E + e]], 1);
}

__global__ void k_scan(const int* __restrict__ deg, int* __restrict__ rp,
                       int* __restrict__ cur, int n){
  __shared__ int part[1024];
  int t = threadIdx.x;
  int K = (n + 1023) >> 10;
  int vals[16];
  int start = t * K;
  int local = 0;
  for (int j = 0; j < K; j++){
    int idx = start + j;
    int v = (idx < n) ? deg[idx] : 0;
    vals[j] = local;
    local += v;
  }
  part[t] = local;
  __syncthreads();
  for (int off = 1; off < 1024; off <<= 1){
    int v = (t >= off) ? part[t - off] : 0;
    __syncthreads();
    part[t] += v;
    __syncthreads();
  }
  int base = part[t] - local;
  for (int j = 0; j < K; j++){
    int idx = start + j;
    if (idx < n){ rp[idx] = base + vals[j]; cur[idx] = base + vals[j]; }
  }
  if (t == 1023) rp[n] = part[1023];
}

__global__ void k_scatter(const int* __restrict__ ei, int* __restrict__ cur,
                          int* __restrict__ col, int E){
  int e = blockIdx.x * blockDim.x + threadIdx.x;
  if (e < E){
    int s = ei[e], d = ei[E + e];
    int p = atomicAdd(&cur[d], 1);
    col[p] = s;
  }
}

// ---------------- conversions ----------------
// fp32 [M,K] -> bf16 [Mpad,K], padding rows zeroed
__global__ void k_cvt_pad(const float* __restrict__ X, unsigned short* __restrict__ Y,
                          int M, int Mpad, int K){
  int idx = blockIdx.x * blockDim.x + threadIdx.x;
  int total = (Mpad * K) >> 2;
  if (idx >= total) return;
  int e = idx << 2;
  int row = e / K;
  ushort4 o;
  if (row < M){
    float4 v = *(const float4*)(X + (size_t)row * K + (e - row * K));
    o.x = f2bf(v.x); o.y = f2bf(v.y); o.z = f2bf(v.z); o.w = f2bf(v.w);
  } else {
    o.x = o.y = o.z = o.w = 0;
  }
  *(ushort4*)(Y + e) = o;
}

// LDS-tiled transpose: fp32 W[K,N] -> bf16 Wt rows [rowOff+n][k]. K,N mult of 32.
__global__ __launch_bounds__(256) void k_tr32(const float* __restrict__ W,
                                              unsigned short* __restrict__ Wt,
                                              int K, int N, int rowOff){
  __shared__ unsigned short tile[32][33];
  int bk = blockIdx.x * 32;
  int bn = blockIdx.y * 32;
  int tx = threadIdx.x & 31;
  int ty = threadIdx.x >> 5;
#pragma unroll
  for (int r = 0; r < 32; r += 8)
    tile[ty + r][tx] = f2bf(W[(size_t)(bk + ty + r) * N + bn + tx]);
  __syncthreads();
#pragma unroll
  for (int r = 0; r < 32; r += 8)
    Wt[(size_t)(rowOff + bn + ty + r) * K + bk + tx] = tile[tx][ty + r];
}

// layer-3 combined weights: Bt[128][K] bf16 (rows 0-35 W3^T, 36-41 Wl3^T, rest 0)
__global__ void k_w3fill(const float* __restrict__ W3, const float* __restrict__ Wl3,
                         const float* __restrict__ bl3, unsigned short* __restrict__ Bt,
                         float* __restrict__ biasc, int K){
  int idx = blockIdx.x * blockDim.x + threadIdx.x;
  if (idx < 48) biasc[idx] = (idx >= 36 && idx < 42) ? bl3[idx - 36] : 0.f;
  if (idx >= 128 * K) return;
  int n = idx / K, k = idx - n * K;
  float v = 0.f;
  if (n < 36) v = W3[(size_t)k * 36 + n];
  else if (n < 42) v = Wl3[(size_t)k * 6 + (n - 36)];
  Bt[idx] = f2bf(v);
}

// ---------------- bf16 MFMA GEMM, swizzled 1D grid, split epilogue ----------------
typedef __attribute__((ext_vector_type(8))) short bf8_t;
typedef __attribute__((ext_vector_type(4))) float f4_t;

__device__ __forceinline__ void async16(const unsigned short* g, unsigned short* l){
  __builtin_amdgcn_global_load_lds(
      (const __attribute__((address_space(1))) void*)g,
      (__attribute__((address_space(3))) void*)l, 16, 0, 0);
}

// grid: 8 * Gm * Ntiles blocks (1D). xcd = b&7 owns m-tiles [xcd*Gm, (xcd+1)*Gm)
// over all n-tiles (n varies slowest within the xcd's sequence).
__global__ __launch_bounds__(256) void k_mfma_gemm(
    const unsigned short* __restrict__ A,
    const unsigned short* __restrict__ Bt,
    const float* __restrict__ bias,
    unsigned short* __restrict__ outBf,
    float* __restrict__ outF,
    int M, int K, int Ntot, int split, int Mtiles, int Gm)
{
  __shared__ unsigned short Asm[128 * 32];
  __shared__ unsigned short Bsm[128 * 32];
  int b = blockIdx.x;
  int xcd = b & 7;
  int j = b >> 3;
  int mloc = j % Gm;
  int n = j / Gm;
  int mtile = xcd * Gm + mloc;
  if (mtile >= Mtiles) return;
  int bm = mtile * 128, bn = n * 128;

  int t = threadIdx.x;
  int w = t >> 6, lane = t & 63;
  int wm = (w >> 1) * 64, wn = (w & 1) * 64;
  int lr = lane & 15, lq = lane >> 4;

  f4_t acc[4][4] = {};

  int srow = lane >> 2;
  int skc  = (lane & 3) << 3;

  for (int k0 = 0; k0 < K; k0 += 32){
#pragma unroll
    for (int r = 0; r < 2; r++){
      int c = r * 4 + w;
      async16(A + (size_t)(bm + c * 16 + srow) * K + k0 + skc, &Asm[c * 512]);
    }
#pragma unroll
    for (int r = 0; r < 2; r++){
      int c = r * 4 + w;
      async16(Bt + (size_t)(bn + c * 16 + srow) * K + k0 + skc, &Bsm[c * 512]);
    }
    __syncthreads();
    bf8_t a[4], bfr[4];
#pragma unroll
    for (int i = 0; i < 4; i++)
      a[i] = *(const bf8_t*)&Asm[(wm + i * 16 + lr) * 32 + lq * 8];
#pragma unroll
    for (int i = 0; i < 4; i++)
      bfr[i] = *(const bf8_t*)&Bsm[(wn + i * 16 + lr) * 32 + lq * 8];
#pragma unroll
    for (int mi = 0; mi < 4; mi++)
#pragma unroll
      for (int ni = 0; ni < 4; ni++)
        acc[mi][ni] = __builtin_amdgcn_mfma_f32_16x16x32_bf16(a[mi], bfr[ni], acc[mi][ni], 0, 0, 0);
    __syncthreads();
  }

  int strideF = Ntot - split;
#pragma unroll
  for (int mi = 0; mi < 4; mi++){
#pragma unroll
    for (int ni = 0; ni < 4; ni++){
      int colg = bn + wn + ni * 16 + lr;
      if (colg >= Ntot) continue;
      bool isF = (colg >= split);
      float bv = isF ? bias[colg - split] : 0.f;
#pragma unroll
      for (int rg = 0; rg < 4; rg++){
        int rowg = bm + wm + mi * 16 + lq * 4 + rg;
        if (rowg < M){
          float v = acc[mi][ni][rg] + bv;
          if (isF) outF[(size_t)rowg * strideF + (colg - split)] = v;
          else outBf[(size_t)rowg * split + colg] = f2bf(v);
        }
      }
    }
  }
}

// ---------------- attention dots (layers 1/2), H in bf16 ----------------
__global__ __launch_bounds__(256) void k_attn_dots(const unsigned short* __restrict__ h,
                                                   const float* __restrict__ a_s,
                                                   const float* __restrict__ a_d,
                                                   float* __restrict__ als,
                                                   float* __restrict__ ald, int N){
  int i = blockIdx.x;
  int t = threadIdx.x;
  float4 hv = loadbf4(h + (size_t)i * 1024 + t * 4);
  float4 sv = ((const float4*)a_s)[t];
  float4 dv = ((const float4*)a_d)[t];
  float ps = hv.x * sv.x + hv.y * sv.y + hv.z * sv.z + hv.w * sv.w;
  float pd = hv.x * dv.x + hv.y * dv.y + hv.z * dv.z + hv.w * dv.w;
#pragma unroll
  for (int off = 32; off >= 1; off >>= 1){
    ps += __shfl_down(ps, off);
    pd += __shfl_down(pd, off);
  }
  if ((t & 63) == 0){
    int w = t >> 6;
    als[i * 4 + w] = ps;
    ald[i * 4 + w] = pd;
  }
}

// ---------------- GAT aggregation (layers 1/2): bf16 out into next GEMM A ------
__global__ __launch_bounds__(256) void k_agg(const unsigned short* __restrict__ H,
                                             const float* __restrict__ Y,
                                             unsigned short* __restrict__ Yout,
                                             const float* __restrict__ bias,
                                             const float* __restrict__ als,
                                             const float* __restrict__ ald,
                                             const int* __restrict__ rp,
                                             const int* __restrict__ col){
  int i = blockIdx.x;
  int t = threadIdx.x;
  int lane = t & 63;
  int w = t >> 6;
  int ro = rp[i];
  int deg = rp[i + 1] - ro;
  __shared__ float sm[4], ss[4];
  __shared__ float s_alpha[64][4];
  __shared__ int s_src[64];

  float aldw = ald[i * 4 + w];
  float eself = leaky(als[i * 4 + w] + aldw);
  float m = eself;
  float s = (lane == 0) ? 1.f : 0.f;
  for (int e = lane; e < deg; e += 64){
    int src = col[ro + e];
    float ev = leaky(als[src * 4 + w] + aldw);
    float M = fmaxf(m, ev);
    s = s * __expf(m - M) + __expf(ev - M);
    m = M;
  }
#pragma unroll
  for (int off = 32; off >= 1; off >>= 1){
    float mo = __shfl_down(m, off);
    float so = __shfl_down(s, off);
    float M = fmaxf(m, mo);
    s = s * __expf(m - M) + so * __expf(mo - M);
    m = M;
  }
  if (lane == 0){ sm[w] = m; ss[w] = s; }
  __syncthreads();

  int head = t >> 6;
  float mh = sm[head];
  float inv = 1.f / (ss[head] + 1e-16f);
  float4 acc = *(const float4*)(Y + (size_t)i * 1024 + t * 4);
  float4 bb  = *(const float4*)(bias + t * 4);
  acc.x += bb.x; acc.y += bb.y; acc.z += bb.z; acc.w += bb.w;
  float aself = __expf(leaky(als[i * 4 + head] + ald[i * 4 + head]) - mh) * inv;
  {
    float4 hv = loadbf4(H + (size_t)i * 1024 + t * 4);
    acc.x += aself * hv.x; acc.y += aself * hv.y;
    acc.z += aself * hv.z; acc.w += aself * hv.w;
  }
  for (int base = 0; base < deg; base += 64){
    __syncthreads();
    if (t < 64 && base + t < deg){
      int src = col[ro + base + t];
      s_src[t] = src;
#pragma unroll
      for (int hh = 0; hh < 4; hh++){
        s_alpha[t][hh] = __expf(leaky(als[src * 4 + hh] + ald[i * 4 + hh]) - sm[hh])
                         / (ss[hh] + 1e-16f);
      }
    }
    __syncthreads();
    int nn = min(64, deg - base);
    for (int e = 0; e < nn; e++){
      float a = s_alpha[e][head];
      float4 hv = loadbf4(H + (size_t)s_src[e] * 1024 + t * 4);
      acc.x += a * hv.x; acc.y += a * hv.y; acc.z += a * hv.z; acc.w += a * hv.w;
    }
  }
  // ELU then bf16 store (next layer's GEMM A)
  acc.x = acc.x > 0.f ? acc.x : expm1f(acc.x);
  acc.y = acc.y > 0.f ? acc.y : expm1f(acc.y);
  acc.z = acc.z > 0.f ? acc.z : expm1f(acc.z);
  acc.w = acc.w > 0.f ? acc.w : expm1f(acc.w);
  ushort4 o;
  o.x = f2bf(acc.x); o.y = f2bf(acc.y); o.z = f2bf(acc.z); o.w = f2bf(acc.w);
  *(ushort4*)(Yout + (size_t)i * 1024 + t * 4) = o;
}

// ---------------- layer-3 attention dots (comb stride 48) ----------------
__global__ void k_attn3(const float* __restrict__ comb, const float* __restrict__ a_s,
                        const float* __restrict__ a_d, float* __restrict__ als,
                        float* __restrict__ ald, int N){
  int i = blockIdx.x * blockDim.x + threadIdx.x;
  if (i >= N) return;
  const float* hp = comb + (size_t)i * 48;
#pragma unroll
  for (int hh = 0; hh < 6; hh++){
    float s = 0.f, d = 0.f;
#pragma unroll
    for (int c = 0; c < 6; c++){
      float v = hp[hh * 6 + c];
      s += v * a_s[hh * 6 + c];
      d += v * a_d[hh * 6 + c];
    }
    als[i * 6 + hh] = s;
    ald[i * 6 + hh] = d;
  }
}

// ---------------- layer 3: GAT(mean heads) + b3 + lin3 + log_softmax ----------------
__global__ __launch_bounds__(64) void k_layer3(const float* __restrict__ comb,
                                               const float* __restrict__ als,
                                               const float* __restrict__ ald,
                                               const float* __restrict__ b3,
                                               const int* __restrict__ rp,
                                               const int* __restrict__ col,
                                               float* __restrict__ out){
  int i = blockIdx.x;
  int lane = threadIdx.x;
  int ro = rp[i], deg = rp[i + 1] - ro;
  float aldv[6], m[6], s[6];
#pragma unroll
  for (int h = 0; h < 6; h++){
    aldv[h] = ald[i * 6 + h];
    float e = leaky(als[i * 6 + h] + aldv[h]);
    m[h] = e;
    s[h] = (lane == 0) ? 1.f : 0.f;
  }
  for (int e = lane; e < deg; e += 64){
    int src = col[ro + e];
#pragma unroll
    for (int h = 0; h < 6; h++){
      float ev = leaky(als[src * 6 + h] + aldv[h]);
      float M = fmaxf(m[h], ev);
      s[h] = s[h] * __expf(m[h] - M) + __expf(ev - M);
      m[h] = M;
    }
  }
#pragma unroll
  for (int off = 32; off >= 1; off >>= 1){
#pragma unroll
    for (int h = 0; h < 6; h++){
      float mo = __shfl_down(m[h], off);
      float so = __shfl_down(s[h], off);
      float M = fmaxf(m[h], mo);
      s[h] = s[h] * __expf(m[h] - M) + so * __expf(mo - M);
      m[h] = M;
    }
  }
#pragma unroll
  for (int h = 0; h < 6; h++){ m[h] = __shfl(m[h], 0); s[h] = __shfl(s[h], 0); }

  __shared__ float o36[36];
  __shared__ float o6[6];
  if (lane < 36){
    int hh = lane / 6, cc = lane - hh * 6;
    float inv = 1.f / (s[hh] + 1e-16f);
    float acc = __expf(leaky(als[i * 6 + hh] + aldv[hh]) - m[hh]) * inv
                * comb[(size_t)i * 48 + hh * 6 + cc];
    for (int e = 0; e < deg; e++){
      int src = col[ro + e];
      float a = __expf(leaky(als[src * 6 + hh] + aldv[hh]) - m[hh]) * inv;
      acc += a * comb[(size_t)src * 48 + hh * 6 + cc];
    }
    o36[lane] = acc;
  }
  __syncthreads();
  if (lane < 6){
    float v = 0.f;
#pragma unroll
    for (int h = 0; h < 6; h++) v += o36[h * 6 + lane];
    o6[lane] = v * (1.f / 6.f) + b3[lane] + comb[(size_t)i * 48 + 36 + lane];
  }
  __syncthreads();
  if (lane == 0){
    float mx = o6[0];
    for (int c = 1; c < 6; c++) mx = fmaxf(mx, o6[c]);
    float se = 0.f;
    for (int c = 0; c < 6; c++) se += __expf(o6[c] - mx);
    float lse = logf(se);
    for (int c = 0; c < 6; c++) out[(size_t)i * 6 + c] = o6[c] - mx - lse;
  }
}

// ---------------------------------------------------------------------------
extern "C" void kernel_launch(void* const* d_in, const int* in_sizes, int n_in,
                              void* d_out, int out_size, void* d_ws, size_t ws_size,
                              hipStream_t stream){
  const float* nf  = (const float*)d_in[0];
  const int*   ei  = (const int*)d_in[1];
  const float* W1  = (const float*)d_in[2];
  const float* as1 = (const float*)d_in[3];
  const float* ad1 = (const float*)d_in[4];
  const float* b1  = (const float*)d_in[5];
  const float* Wl1 = (const float*)d_in[6];
  const float* bl1 = (const float*)d_in[7];
  const float* W2  = (const float*)d_in[8];
  const float* as2 = (const float*)d_in[9];
  const float* ad2 = (const float*)d_in[10];
  const float* b2  = (const float*)d_in[11];
  const float* Wl2 = (const float*)d_in[12];
  const float* bl2 = (const float*)d_in[13];
  const float* W3  = (const float*)d_in[14];
  const float* as3 = (const float*)d_in[15];
  const float* ad3 = (const float*)d_in[16];
  const float* b3  = (const float*)d_in[17];
  const float* Wl3 = (const float*)d_in[18];
  const float* bl3 = (const float*)d_in[19];
  float* out = (float*)d_out;

  const int N = in_sizes[0] / 512;   // 10000
  const int E = in_sizes[1] / 2;     // 160000
  const int Mpad = ((N + 127) / 128) * 128;   // 10112
  const int Mtiles = Mpad / 128;              // 79
  const int Gm = (Mtiles + 7) / 8;            // 10

  char* ws = (char*)d_ws;
  size_t off = 0;
  auto alloc = [&](size_t bytes) -> char* {
    char* p = ws + off;
    off += (bytes + 255) & ~(size_t)255;
    return p;
  };
  unsigned short* Abf1 = (unsigned short*)alloc((size_t)Mpad * 512 * 2);   // layer-1 A
  unsigned short* Abf2 = (unsigned short*)alloc((size_t)Mpad * 1024 * 2);  // layer-2/3 A
  unsigned short* Hbf  = (unsigned short*)alloc((size_t)N * 1024 * 2);     // attn features
  float* Bb    = (float*)alloc((size_t)N * 1024 * 4);                      // linear path fp32
  float* comb  = (float*)alloc((size_t)N * 48 * 4);                        // layer-3 [h3|lin3]
  float* als   = (float*)alloc((size_t)N * 8 * 4);
  float* ald   = (float*)alloc((size_t)N * 8 * 4);
  float* biasc = (float*)alloc(48 * 4);
  int* deg     = (int*)alloc((size_t)N * 4);
  int* rp      = (int*)alloc((size_t)(N + 1) * 4);
  int* cur     = (int*)alloc((size_t)N * 4);
  int* colx    = (int*)alloc((size_t)E * 4);
  unsigned short* Wc1 = (unsigned short*)alloc((size_t)2048 * 512 * 2);
  unsigned short* Wc2 = (unsigned short*)alloc((size_t)2048 * 1024 * 2);
  unsigned short* Bt3 = (unsigned short*)alloc((size_t)128 * 1024 * 2);

  // CSR build + pad-row zeroing for Abf2 (k_agg only writes rows < N)
  hipMemsetAsync(deg, 0, (size_t)N * 4, stream);
  hipMemsetAsync(Abf2 + (size_t)N * 1024, 0, (size_t)(Mpad - N) * 1024 * 2, stream);
  k_count  <<<(E + 255) / 256, 256, 0, stream>>>(ei, deg, E);
  k_scan   <<<1, 1024, 0, stream>>>(deg, rp, cur, N);
  k_scatter<<<(E + 255) / 256, 256, 0, stream>>>(ei, cur, colx, E);

  // weight prep
  k_tr32<<<dim3(512 / 32, 1024 / 32), 256, 0, stream>>>(W1, Wc1, 512, 1024, 0);
  k_tr32<<<dim3(512 / 32, 1024 / 32), 256, 0, stream>>>(Wl1, Wc1, 512, 1024, 1024);
  k_tr32<<<dim3(1024 / 32, 1024 / 32), 256, 0, stream>>>(W2, Wc2, 1024, 1024, 0);
  k_tr32<<<dim3(1024 / 32, 1024 / 32), 256, 0, stream>>>(W2 == Wl2 ? Wl2 : Wl2, Wc2, 1024, 1024, 1024);
  k_w3fill<<<(128 * 1024 + 255) / 256, 256, 0, stream>>>(W3, Wl3, bl3, Bt3, biasc, 1024);

  int blocksL = 8 * Gm * 16;   // N=2048 (16 n-tiles)
  int blocks3 = 8 * Gm * 1;

  // layer 1
  k_cvt_pad<<<(Mpad * 512 / 4 + 255) / 256, 256, 0, stream>>>(nf, Abf1, N, Mpad, 512);
  k_mfma_gemm<<<blocksL, 256, 0, stream>>>(Abf1, Wc1, bl1, Hbf, Bb, N, 512, 2048, 1024, Mtiles, Gm);
  k_attn_dots<<<N, 256, 0, stream>>>(Hbf, as1, ad1, als, ald, N);
  k_agg<<<N, 256, 0, stream>>>(Hbf, Bb, Abf2, b1, als, ald, rp, colx);

  // layer 2
  k_mfma_gemm<<<blocksL, 256, 0, stream>>>(Abf2, Wc2, bl2, Hbf, Bb, N, 1024, 2048, 1024, Mtiles, Gm);
  k_attn_dots<<<N, 256, 0, stream>>>(Hbf, as2, ad2, als, ald, N);
  k_agg<<<N, 256, 0, stream>>>(Hbf, Bb, Abf2, b2, als, ald, rp, colx);

  // layer 3
  k_mfma_gemm<<<blocks3, 256, 0, stream>>>(Abf2, Bt3, biasc, nullptr, comb, N, 1024, 48, 0, Mtiles, Gm);
  k_attn3<<<(N + 255) / 256, 256, 0, stream>>>(comb, as3, ad3, als, ald, N);
  k_layer3<<<N, 64, 0, stream>>>(comb, als, ald, b3, rp, colx, out);
}